// Round 2
// baseline (95764.856 us; speedup 1.0000x reference)
//
#include <hip/hip_runtime.h>

// LSTM: S=512 steps, B=64 batch, I=256 in, H=512 hidden. All tensors FLOAT32
// (R1's NaN proved buffers are f32: reading f32 as bf16 pairs yields inf/NaN
// bit patterns in the odd elements; genuine bf16 inputs could not NaN here).
//
// R2 design: one workgroup per batch element (batch rows are independent ->
// zero cross-WG sync), 512 threads = 1 thread per hidden unit, x/h staged in
// LDS per step, c in a register. float4 weight loads, ds_read_b128 broadcasts.

#define SS 512
#define BB 64
#define II 256
#define HH 512

typedef __attribute__((ext_vector_type(4))) float f32x4;

__device__ __forceinline__ float sigmoid_f(float v) { return 1.0f / (1.0f + __expf(-v)); }
__device__ __forceinline__ float tanh_f(float v)    { return 1.0f - 2.0f / (1.0f + __expf(2.0f * v)); }

__global__ __launch_bounds__(HH, 1) void lstm_fused(
    const float* __restrict__ x,   const float* __restrict__ h0,  const float* __restrict__ c0,
    const float* __restrict__ Wfi, const float* __restrict__ bfi,
    const float* __restrict__ Wfh, const float* __restrict__ bfh,
    const float* __restrict__ Wii, const float* __restrict__ bii,
    const float* __restrict__ Wih, const float* __restrict__ bih,
    const float* __restrict__ Wci, const float* __restrict__ bci,
    const float* __restrict__ Wch, const float* __restrict__ bch,
    const float* __restrict__ Woi, const float* __restrict__ boi,
    const float* __restrict__ Woh, const float* __restrict__ boh,
    float* __restrict__ out)
{
    const int b = blockIdx.x;   // batch element
    const int j = threadIdx.x;  // hidden unit

    __shared__ float xs[II];
    __shared__ float hs[HH];

    // init state
    hs[j] = h0[b * HH + j];
    float c = c0[b * HH + j];

    // pre-combined biases (bfi + bfh etc.)
    const float bf_ = bfi[j] + bfh[j];
    const float bi_ = bii[j] + bih[j];
    const float bc_ = bci[j] + bch[j];
    const float bo_ = boi[j] + boh[j];

    // row pointers for this thread's hidden unit (rows are 16B-aligned)
    const float* wfx = Wfi + j * II;
    const float* wix = Wii + j * II;
    const float* wcx = Wci + j * II;
    const float* wox = Woi + j * II;
    const float* wfh = Wfh + j * HH;
    const float* wih = Wih + j * HH;
    const float* wch = Wch + j * HH;
    const float* woh = Woh + j * HH;

    float hnew = 0.0f;

    for (int t = 0; t < SS; ++t) {
        // publish state for step t (previous step's reads were fenced by the
        // barrier at the bottom of the loop)
        if (t) hs[j] = hnew;
        if (j < II) xs[j] = x[(t * BB + b) * II + j];
        __syncthreads();

        float af = bf_, ai = bi_, ac = bc_, ao = bo_;

        // x-part: K = 256
        #pragma unroll 4
        for (int k = 0; k < II; k += 4) {
            const f32x4 wf = *(const f32x4*)(wfx + k);
            const f32x4 wi = *(const f32x4*)(wix + k);
            const f32x4 wc = *(const f32x4*)(wcx + k);
            const f32x4 wo = *(const f32x4*)(wox + k);
            const f32x4 xv = *(const f32x4*)(xs + k);   // LDS broadcast
            #pragma unroll
            for (int r = 0; r < 4; ++r) {
                af = fmaf(wf[r], xv[r], af);
                ai = fmaf(wi[r], xv[r], ai);
                ac = fmaf(wc[r], xv[r], ac);
                ao = fmaf(wo[r], xv[r], ao);
            }
        }

        // h-part: K = 512
        #pragma unroll 4
        for (int k = 0; k < HH; k += 4) {
            const f32x4 wf = *(const f32x4*)(wfh + k);
            const f32x4 wi = *(const f32x4*)(wih + k);
            const f32x4 wc = *(const f32x4*)(wch + k);
            const f32x4 wo = *(const f32x4*)(woh + k);
            const f32x4 hv = *(const f32x4*)(hs + k);   // LDS broadcast
            #pragma unroll
            for (int r = 0; r < 4; ++r) {
                af = fmaf(wf[r], hv[r], af);
                ai = fmaf(wi[r], hv[r], ai);
                ac = fmaf(wc[r], hv[r], ac);
                ao = fmaf(wo[r], hv[r], ao);
            }
        }

        const float fg = sigmoid_f(af);
        const float ig = sigmoid_f(ai);
        const float cg = tanh_f(ac);
        const float og = sigmoid_f(ao);

        c = c * fg + ig * cg;
        hnew = og * tanh_f(c);

        out[(t * BB + b) * HH + j] = hnew;

        __syncthreads();  // all reads of xs/hs for step t complete before overwrite
    }

    // final h and c, concatenated after h_seq
    out[SS * BB * HH + b * HH + j]           = hnew;
    out[SS * BB * HH + BB * HH + b * HH + j] = c;
}

extern "C" void kernel_launch(void* const* d_in, const int* in_sizes, int n_in,
                              void* d_out, int out_size, void* d_ws, size_t ws_size,
                              hipStream_t stream) {
    const float* x   = (const float*)d_in[0];
    const float* h0  = (const float*)d_in[1];
    const float* c0  = (const float*)d_in[2];
    const float* Wfi = (const float*)d_in[3];
    const float* bfi = (const float*)d_in[4];
    const float* Wfh = (const float*)d_in[5];
    const float* bfh = (const float*)d_in[6];
    const float* Wii = (const float*)d_in[7];
    const float* bii = (const float*)d_in[8];
    const float* Wih = (const float*)d_in[9];
    const float* bih = (const float*)d_in[10];
    const float* Wci = (const float*)d_in[11];
    const float* bci = (const float*)d_in[12];
    const float* Wch = (const float*)d_in[13];
    const float* bch = (const float*)d_in[14];
    const float* Woi = (const float*)d_in[15];
    const float* boi = (const float*)d_in[16];
    const float* Woh = (const float*)d_in[17];
    const float* boh = (const float*)d_in[18];

    lstm_fused<<<dim3(BB), dim3(HH), 0, stream>>>(
        x, h0, c0,
        Wfi, bfi, Wfh, bfh,
        Wii, bii, Wih, bih,
        Wci, bci, Wch, bch,
        Woi, boi, Woh, boh,
        (float*)d_out);
}

// Round 3
// 11169.718 us; speedup vs baseline: 8.5736x; 8.5736x over previous
//
#include <hip/hip_runtime.h>

// LSTM: S=512, B=64, I=256, H=512. f32 buffers (proven R2).
// R3: fix uncoalesced weight reads (R2: VALUBusy 2%, 64-way transaction fanout
// per wave-load -> 93 ms). One-time prep kernel repacks weights as f16 pairs,
// K-major + gate-interleaved: WT[k2][j][g]. Main loop: per-thread dwordx4 load
// is coalesced (wave = 1KB contiguous); v_dot2_f32_f16 = 2 MAC/VALU op.
// Weights f16 = 3.15 MB -> L2-resident per XCD across steps.

#define SS 512
#define BB 64
#define II 256
#define HH 512

typedef unsigned int uint32;
typedef uint32 __attribute__((ext_vector_type(4))) u32x4;
typedef _Float16 __attribute__((ext_vector_type(2))) h2;
typedef __attribute__((ext_vector_type(2))) float f32x2;
typedef __attribute__((ext_vector_type(4))) float f32x4;

__device__ __forceinline__ h2 u2h(uint32 u) { union { uint32 u; h2 h; } v; v.u = u; return v.h; }

#if __has_builtin(__builtin_amdgcn_fdot2)
__device__ __forceinline__ float FDOT2(h2 a, h2 b, float c) {
    return __builtin_amdgcn_fdot2(a, b, c, false);
}
#else
__device__ __forceinline__ float FDOT2(h2 a, h2 b, float c) {
    return fmaf((float)a.x, (float)b.x, fmaf((float)a.y, (float)b.y, c));
}
#endif

__device__ __forceinline__ float sigmoid_f(float v) { return 1.0f / (1.0f + __expf(-v)); }
__device__ __forceinline__ float tanh_f(float v)    { return 1.0f - 2.0f / (1.0f + __expf(2.0f * v)); }

// ---------------- preprocess: f32 row-major (H,K) -> f16-pair WT[k2][j][g] ----------------
// Output dword index == tid. tids [0, 128*512*4)   : x-weights, k2 in [0,128)
//                            [128*512*4, +256*512*4): h-weights, k2 in [0,256)
__global__ __launch_bounds__(256) void prep_weights(
    const float* __restrict__ Wfi, const float* __restrict__ Wii,
    const float* __restrict__ Wci, const float* __restrict__ Woi,
    const float* __restrict__ Wfh, const float* __restrict__ Wih,
    const float* __restrict__ Wch, const float* __restrict__ Woh,
    uint32* __restrict__ ws)
{
    const int tid = blockIdx.x * 256 + threadIdx.x;   // 0..786431
    const int g  = tid & 3;
    const int j  = (tid >> 2) & (HH - 1);
    const int k2 = tid >> 11;

    const float* W;
    int K, kk;
    if (k2 < II / 2) {
        K = II; kk = k2;
        W = (g == 0) ? Wfi : (g == 1) ? Wii : (g == 2) ? Wci : Woi;
    } else {
        K = HH; kk = k2 - II / 2;
        W = (g == 0) ? Wfh : (g == 1) ? Wih : (g == 2) ? Wch : Woh;
    }
    const float w0 = W[j * K + 2 * kk];
    const float w1 = W[j * K + 2 * kk + 1];
    union { h2 h; uint32 u; } p;
    p.h.x = (_Float16)w0;
    p.h.y = (_Float16)w1;
    ws[tid] = p.u;
}

// ---------------- main recurrent kernel ----------------
__global__ __launch_bounds__(HH, 1) void lstm_f16(
    const float* __restrict__ x, const float* __restrict__ h0, const float* __restrict__ c0,
    const float* __restrict__ bfi, const float* __restrict__ bfh,
    const float* __restrict__ bii, const float* __restrict__ bih,
    const float* __restrict__ bci, const float* __restrict__ bch,
    const float* __restrict__ boi, const float* __restrict__ boh,
    const u32x4* __restrict__ XT,  // [128][512] dwordx4
    const u32x4* __restrict__ HT,  // [256][512] dwordx4
    float* __restrict__ out)
{
    const int b = blockIdx.x;
    const int j = threadIdx.x;

    __shared__ _Float16 xs16[II];
    __shared__ _Float16 hs16[HH];

    hs16[j] = (_Float16)h0[b * HH + j];
    float c = c0[b * HH + j];

    const float bf_ = bfi[j] + bfh[j];
    const float bi_ = bii[j] + bih[j];
    const float bc_ = bci[j] + bch[j];
    const float bo_ = boi[j] + boh[j];

    const u32x4* Xrow = XT + j;   // stride HH per k2
    const u32x4* Hrow = HT + j;

    float hnew = 0.0f;

    for (int t = 0; t < SS; ++t) {
        if (j < II / 2) {
            const f32x2 xv = ((const f32x2*)(x + (t * BB + b) * II))[j];
            xs16[2 * j]     = (_Float16)xv.x;
            xs16[2 * j + 1] = (_Float16)xv.y;
        }
        __syncthreads();   // fences xs stage + hs write from prev iter

        float af = bf_, ai = bi_, ac = bc_, ao = bo_;

        // x-part: 128 k-pairs
        #pragma unroll 8
        for (int k2 = 0; k2 < II / 2; ++k2) {
            const u32x4 w = Xrow[k2 * HH];
            const h2 s = *(const h2*)(xs16 + 2 * k2);   // LDS broadcast
            af = FDOT2(u2h(w[0]), s, af);
            ai = FDOT2(u2h(w[1]), s, ai);
            ac = FDOT2(u2h(w[2]), s, ac);
            ao = FDOT2(u2h(w[3]), s, ao);
        }

        // h-part: 256 k-pairs
        #pragma unroll 8
        for (int k2 = 0; k2 < HH / 2; ++k2) {
            const u32x4 w = Hrow[k2 * HH];
            const h2 s = *(const h2*)(hs16 + 2 * k2);   // LDS broadcast
            af = FDOT2(u2h(w[0]), s, af);
            ai = FDOT2(u2h(w[1]), s, ai);
            ac = FDOT2(u2h(w[2]), s, ac);
            ao = FDOT2(u2h(w[3]), s, ao);
        }

        const float fg = sigmoid_f(af);
        const float ig = sigmoid_f(ai);
        const float cg = tanh_f(ac);
        const float og = sigmoid_f(ao);

        c = c * fg + ig * cg;
        hnew = og * tanh_f(c);

        out[(t * BB + b) * HH + j] = hnew;

        __syncthreads();   // all reads of xs/hs done before overwrite
        hs16[j] = (_Float16)hnew;
    }

    out[SS * BB * HH + b * HH + j]           = hnew;
    out[SS * BB * HH + BB * HH + b * HH + j] = c;
}

// ---------------- fallback (R2, f32 direct) if ws too small ----------------
__global__ __launch_bounds__(HH, 1) void lstm_fallback(
    const float* __restrict__ x,   const float* __restrict__ h0,  const float* __restrict__ c0,
    const float* __restrict__ Wfi, const float* __restrict__ bfi,
    const float* __restrict__ Wfh, const float* __restrict__ bfh,
    const float* __restrict__ Wii, const float* __restrict__ bii,
    const float* __restrict__ Wih, const float* __restrict__ bih,
    const float* __restrict__ Wci, const float* __restrict__ bci,
    const float* __restrict__ Wch, const float* __restrict__ bch,
    const float* __restrict__ Woi, const float* __restrict__ boi,
    const float* __restrict__ Woh, const float* __restrict__ boh,
    float* __restrict__ out)
{
    const int b = blockIdx.x;
    const int j = threadIdx.x;
    __shared__ float xs[II];
    __shared__ float hs[HH];
    hs[j] = h0[b * HH + j];
    float c = c0[b * HH + j];
    const float bf_ = bfi[j] + bfh[j];
    const float bi_ = bii[j] + bih[j];
    const float bc_ = bci[j] + bch[j];
    const float bo_ = boi[j] + boh[j];
    const float* wfx = Wfi + j * II;
    const float* wix = Wii + j * II;
    const float* wcx = Wci + j * II;
    const float* wox = Woi + j * II;
    const float* wfh = Wfh + j * HH;
    const float* wih = Wih + j * HH;
    const float* wch = Wch + j * HH;
    const float* woh = Woh + j * HH;
    float hnew = 0.0f;
    for (int t = 0; t < SS; ++t) {
        if (t) hs[j] = hnew;
        if (j < II) xs[j] = x[(t * BB + b) * II + j];
        __syncthreads();
        float af = bf_, ai = bi_, ac = bc_, ao = bo_;
        #pragma unroll 4
        for (int k = 0; k < II; k += 4) {
            const f32x4 wf = *(const f32x4*)(wfx + k);
            const f32x4 wi = *(const f32x4*)(wix + k);
            const f32x4 wc = *(const f32x4*)(wcx + k);
            const f32x4 wo = *(const f32x4*)(wox + k);
            const f32x4 xv = *(const f32x4*)(xs + k);
            #pragma unroll
            for (int r = 0; r < 4; ++r) {
                af = fmaf(wf[r], xv[r], af);
                ai = fmaf(wi[r], xv[r], ai);
                ac = fmaf(wc[r], xv[r], ac);
                ao = fmaf(wo[r], xv[r], ao);
            }
        }
        #pragma unroll 4
        for (int k = 0; k < HH; k += 4) {
            const f32x4 wf = *(const f32x4*)(wfh + k);
            const f32x4 wi = *(const f32x4*)(wih + k);
            const f32x4 wc = *(const f32x4*)(wch + k);
            const f32x4 wo = *(const f32x4*)(woh + k);
            const f32x4 hv = *(const f32x4*)(hs + k);
            #pragma unroll
            for (int r = 0; r < 4; ++r) {
                af = fmaf(wf[r], hv[r], af);
                ai = fmaf(wi[r], hv[r], ai);
                ac = fmaf(wc[r], hv[r], ac);
                ao = fmaf(wo[r], hv[r], ao);
            }
        }
        const float fg = sigmoid_f(af);
        const float ig = sigmoid_f(ai);
        const float cg = tanh_f(ac);
        const float og = sigmoid_f(ao);
        c = c * fg + ig * cg;
        hnew = og * tanh_f(c);
        out[(t * BB + b) * HH + j] = hnew;
        __syncthreads();
    }
    out[SS * BB * HH + b * HH + j]           = hnew;
    out[SS * BB * HH + BB * HH + b * HH + j] = c;
}

extern "C" void kernel_launch(void* const* d_in, const int* in_sizes, int n_in,
                              void* d_out, int out_size, void* d_ws, size_t ws_size,
                              hipStream_t stream) {
    const float* x   = (const float*)d_in[0];
    const float* h0  = (const float*)d_in[1];
    const float* c0  = (const float*)d_in[2];
    const float* Wfi = (const float*)d_in[3];
    const float* bfi = (const float*)d_in[4];
    const float* Wfh = (const float*)d_in[5];
    const float* bfh = (const float*)d_in[6];
    const float* Wii = (const float*)d_in[7];
    const float* bii = (const float*)d_in[8];
    const float* Wih = (const float*)d_in[9];
    const float* bih = (const float*)d_in[10];
    const float* Wci = (const float*)d_in[11];
    const float* bci = (const float*)d_in[12];
    const float* Wch = (const float*)d_in[13];
    const float* bch = (const float*)d_in[14];
    const float* Woi = (const float*)d_in[15];
    const float* boi = (const float*)d_in[16];
    const float* Woh = (const float*)d_in[17];
    const float* boh = (const float*)d_in[18];

    const size_t need = (size_t)(II / 2 + HH / 2) * HH * 4 * sizeof(uint32);  // 3.15 MB
    if (ws_size >= need) {
        uint32* ws = (uint32*)d_ws;
        prep_weights<<<dim3((II / 2 + HH / 2) * HH * 4 / 256), dim3(256), 0, stream>>>(
            Wfi, Wii, Wci, Woi, Wfh, Wih, Wch, Woh, ws);
        const u32x4* XT = (const u32x4*)ws;
        const u32x4* HT = (const u32x4*)(ws + (size_t)(II / 2) * HH * 4);
        lstm_f16<<<dim3(BB), dim3(HH), 0, stream>>>(
            x, h0, c0,
            bfi, bfh, bii, bih, bci, bch, boi, boh,
            XT, HT, (float*)d_out);
    } else {
        lstm_fallback<<<dim3(BB), dim3(HH), 0, stream>>>(
            x, h0, c0,
            Wfi, bfi, Wfh, bfh,
            Wii, bii, Wih, bih,
            Wci, bci, Wch, bch,
            Woi, boi, Woh, boh,
            (float*)d_out);
    }
}

// Round 4
// 7986.508 us; speedup vs baseline: 11.9908x; 1.3986x over previous
//
#include <hip/hip_runtime.h>

// LSTM S=512,B=64,I=256,H=512 (f32 buffers).
// R4: R3's wall was the per-CU L1<->L2 port (3.15MB weights restreamed per
// step = 20.6us/step). Fix: 32 persistent WGs, each owns 64 gate-rows
// (16 hidden x 4 gates); weights packed once (prep kernel) into f16 MFMA
// A-fragments and held in VGPRs (96/lane). Per step: 64x64 GEMM K=768 via
// v_mfma_f32_32x32x16_f16 (B = [x_t;h] staged in swizzled LDS), gate
// exchange via LDS atomics, h broadcast via double-buffered global f16
// buffer + device-scope flag barrier. Weight L2 traffic per step: zero.

#define SS 512
#define BB 64
#define II 256
#define HH 512
#define NWG 32
#define KT 24            // K-tiles of 16 per wave (K/2 = 384)

typedef unsigned int u32;
typedef unsigned short u16;
typedef _Float16 __attribute__((ext_vector_type(8))) h16x8;
typedef __attribute__((ext_vector_type(4))) float f32x4;
typedef __attribute__((ext_vector_type(16))) float f32x16;
typedef u32 __attribute__((ext_vector_type(4))) u32x4;

// ws layout (bytes): [A frags: 3,145,728][hb: 2*65,536][flags: 2048]
#define A_DWORDS (NWG * 2 * 2 * KT * 64 * 4)          // 786432
#define HB_OFF   ((size_t)A_DWORDS * 4)               // 3,145,728
#define FL_OFF   (HB_OFF + 2 * (size_t)BB * HH * 2)   // +131,072
#define WS_NEED  (FL_OFF + 2048)

__device__ __forceinline__ u32 pk2h(float a, float b) {
    union { _Float16 h[2]; u32 u; } v;
    v.h[0] = (_Float16)a; v.h[1] = (_Float16)b; return v.u;
}
__device__ __forceinline__ u16 f2h(float a) {
    union { _Float16 h; u16 u; } v; v.h = (_Float16)a; return v.u;
}
__device__ __forceinline__ float sigf(float v)  { return 1.0f / (1.0f + __expf(-v)); }
__device__ __forceinline__ float tanhf_(float v){ return 1.0f - 2.0f / (1.0f + __expf(2.0f * v)); }

// ---------- prep: pack W into per-lane A-fragments (f16), K-major ----------
// A dword index = ((((wg*2+mt)*2+ks)*KT+kt)*64+l)*4+d
// A[m][k]: m = l&31 (row_local), k-half = l>>5; row = mt*32+row_local;
// gate g = row>>4, hidden j = wg*16 + (row&15); k = ks*384 + kt*16 + (l>>5)*8 + d*2 + e
__global__ __launch_bounds__(256) void prep_A(
    const float* __restrict__ Wfi, const float* __restrict__ Wfh,
    const float* __restrict__ Wii, const float* __restrict__ Wih,
    const float* __restrict__ Wci, const float* __restrict__ Wch,
    const float* __restrict__ Woi, const float* __restrict__ Woh,
    u32* __restrict__ A)
{
    int tid = blockIdx.x * 256 + threadIdx.x;          // < 786432
    int wg = tid / 24576;  int r = tid - wg * 24576;
    int mt = r / 12288;    r -= mt * 12288;
    int ks = r / 6144;     r -= ks * 6144;
    int kt = r / 256;      r -= kt * 256;
    int l  = r >> 2;       int d = r & 3;

    int row = mt * 32 + (l & 31);
    int g   = row >> 4;
    int j   = wg * 16 + (row & 15);
    int k   = ks * 384 + kt * 16 + (l >> 5) * 8 + d * 2;

    const float* Wi = (g == 0) ? Wfi : (g == 1) ? Wii : (g == 2) ? Wci : Woi;
    const float* Wh = (g == 0) ? Wfh : (g == 1) ? Wih : (g == 2) ? Wch : Woh;
    float w0, w1;
    if (k < II) { w0 = Wi[j * II + k];        w1 = Wi[j * II + k + 1]; }
    else        { int kk = k - II; w0 = Wh[j * HH + kk]; w1 = Wh[j * HH + kk + 1]; }
    A[tid] = pk2h(w0, w1);
}

// ---------- prep: h0 -> f16 broadcast buffer, zero barrier flags ----------
__global__ __launch_bounds__(256) void prep_misc(
    const float* __restrict__ h0, u16* __restrict__ hb, int* __restrict__ flags)
{
    int tid = blockIdx.x * 256 + threadIdx.x;          // < 32768
    if (tid < BB * HH) {
        int b = tid >> 9, j = tid & 511;
        hb[(j >> 3) * 512 + b * 8 + (j & 7)] = f2h(h0[tid]);
    }
    if (tid < NWG) flags[tid * 16] = 0;
}

// ---------- main persistent cooperative kernel ----------
__global__ __launch_bounds__(512, 1) void lstm_mfma(
    const float* __restrict__ x,  const float* __restrict__ c0,
    const float* __restrict__ bfi, const float* __restrict__ bfh,
    const float* __restrict__ bii, const float* __restrict__ bih,
    const float* __restrict__ bci, const float* __restrict__ bch,
    const float* __restrict__ boi, const float* __restrict__ boh,
    const u32* __restrict__ A, u16* __restrict__ hb, int* __restrict__ flags,
    float* __restrict__ out)
{
    const int wg   = blockIdx.x;
    const int tid  = threadIdx.x;
    const int lane = tid & 63;
    const int w    = tid >> 6;
    const int mt   = w & 1;          // row-tile (32 gate-rows)
    const int nt2  = (w >> 1) & 1;   // batch-tile (32 batches)
    const int ks   = w >> 2;         // k-split half (K=384 each)
    const int khi  = lane >> 5;      // k-subhalf within fragment
    const int nb   = nt2 * 32 + (lane & 31);  // batch column this lane computes

    // BS chunks of 8 f16 (16B): [0,2048)=x buf0, [2048,4096)=x buf1, [4096,8192)=h
    __shared__ __align__(16) u16 BS[8192 * 8];
    __shared__ float GL[4096];       // [gate][16 m][64 b] f32

    char* BSc = (char*)BS;

    // --- load A fragments (held in VGPRs for the whole kernel) ---
    h16x8 afr[KT];
    {
        const u32* ab = A + ((wg * 2 + mt) * 2 + ks) * (KT * 256) + lane * 4;
        #pragma unroll
        for (int kt = 0; kt < KT; ++kt)
            afr[kt] = *(const h16x8*)(ab + kt * 256);
    }

    // --- accumulator init: combined biases (only ks==0 carries bias) ---
    f32x16 acc_init;
    #pragma unroll
    for (int rg = 0; rg < 16; ++rg) {
        int row = mt * 32 + (rg & 3) + 8 * (rg >> 2) + 4 * khi;
        float bv = 0.0f;
        if (ks == 0) {
            int g = row >> 4, j = wg * 16 + (row & 15);
            const float* bi = (g == 0) ? bfi : (g == 1) ? bii : (g == 2) ? bci : boi;
            const float* bh = (g == 0) ? bfh : (g == 1) ? bih : (g == 2) ? bch : boh;
            bv = bi[j] + bh[j];
        }
        acc_init[rg] = bv;
    }

    // --- c state: thread owns (b = tid&63, m = tid>>6 (+8)) ---
    float cst[2];
    #pragma unroll
    for (int i = 0; i < 2; ++i) {
        int b = tid & 63, m = (tid >> 6) + i * 8;
        cst[i] = c0[b * HH + wg * 16 + m];
    }

    // --- stage x_0 into x buf 0 ---
    #pragma unroll
    for (int i = 0; i < 4; ++i) {
        int cid = i * 512 + tid;
        int b = cid >> 5, k8 = cid & 31;
        const f32x4* sp = (const f32x4*)(x + b * II + k8 * 8);
        f32x4 v0 = sp[0], v1 = sp[1];
        u32x4 pk;
        pk.x = pk2h(v0[0], v0[1]); pk.y = pk2h(v0[2], v0[3]);
        pk.z = pk2h(v1[0], v1[1]); pk.w = pk2h(v1[2], v1[3]);
        *(u32x4*)&BSc[(k8 * 64 + (b ^ (k8 & 7))) * 16] = pk;
    }

    for (int t = 0; t < SS; ++t) {
        const int cur = t & 1;

        // (A) restage h from hb[cur] into BS h region (chunks 4096..8191)
        {
            const u16* hsrc = hb + cur * (BB * HH);
            #pragma unroll
            for (int p = 0; p < 2; ++p) {
                u32x4 hr[4];
                #pragma unroll
                for (int it = 0; it < 4; ++it) {
                    int cd = (p * 4 + it) * 512 + tid;          // 0..4095
                    int k8h = cd >> 6, bpos = cd & 63;
                    int b = bpos ^ (k8h & 7);
                    hr[it] = *(const u32x4*)(hsrc + k8h * 512 + b * 8);
                }
                #pragma unroll
                for (int it = 0; it < 4; ++it) {
                    int cd = (p * 4 + it) * 512 + tid;
                    *(u32x4*)&BSc[(4096 + cd) * 16] = hr[it];
                }
            }
        }

        // x prefetch t+1 (issue global loads; convert+write at (G))
        f32x4 xv[8];
        if (t + 1 < SS) {
            const float* xt = x + (size_t)(t + 1) * BB * II;
            #pragma unroll
            for (int i = 0; i < 4; ++i) {
                int cid = i * 512 + tid;
                int b = cid >> 5, k8 = cid & 31;
                const f32x4* sp = (const f32x4*)(xt + b * II + k8 * 8);
                xv[2 * i] = sp[0]; xv[2 * i + 1] = sp[1];
            }
        }

        // zero the gate-exchange buffer
        {
            f32x4 z = {0.f, 0.f, 0.f, 0.f};
            *(f32x4*)&GL[tid * 8]     = z;
            *(f32x4*)&GL[tid * 8 + 4] = z;
        }

        __syncthreads();   // (B) h staged, x buf cur valid, GL zeroed

        // (C) K-loop: 24 MFMAs (K=384 per k-split half)
        f32x16 acc = acc_init;
        #pragma unroll
        for (int kt = 0; kt < KT; ++kt) {
            int k8g = ks * 48 + kt * 2 + khi;
            int off;
            if (k8g < 32) { int q = k8g & 7;                     // x region
                off = (cur * 2048 + k8g * 64 + ((nb ^ q))) * 16;
            } else {        int k8h = k8g - 32; int q = k8h & 7; // h region
                off = (4096 + k8h * 64 + ((nb ^ q))) * 16;
            }
            h16x8 bf = *(const h16x8*)(BSc + off);
            acc = __builtin_amdgcn_mfma_f32_32x32x16_f16(afr[kt], bf, acc, 0, 0, 0);
        }

        // accumulate k-split halves + cross-wave exchange via LDS atomics
        #pragma unroll
        for (int rg = 0; rg < 16; ++rg) {
            int row = mt * 32 + (rg & 3) + 8 * (rg >> 2) + 4 * khi;
            atomicAdd(&GL[row * 64 + nb], acc[rg]);  // row = g*16+m
        }
        __syncthreads();   // (D)

        // (E) pointwise: c/h update for (b = tid&63, m = tid>>6 (+8))
        #pragma unroll
        for (int i = 0; i < 2; ++i) {
            int b = tid & 63, m = (tid >> 6) + i * 8;
            int j = wg * 16 + m;
            float fg = sigf (GL[(0 * 16 + m) * 64 + b]);
            float ig = sigf (GL[(1 * 16 + m) * 64 + b]);
            float cg = tanhf_(GL[(2 * 16 + m) * 64 + b]);
            float og = sigf (GL[(3 * 16 + m) * 64 + b]);
            float cn = cst[i] * fg + ig * cg;
            cst[i] = cn;
            float hv = og * tanhf_(cn);
            out[((size_t)t * BB + b) * HH + j] = hv;
            hb[((t + 1) & 1) * (BB * HH) + (j >> 3) * 512 + b * 8 + (j & 7)] = f2h(hv);
            if (t == SS - 1) {
                out[(size_t)SS * BB * HH + b * HH + j] = hv;
                out[(size_t)SS * BB * HH + BB * HH + b * HH + j] = cn;
            }
        }
        if (t == SS - 1) break;

        // (F) publish: all stores drained at barrier, then release flag
        __syncthreads();
        if (tid == 0)
            __hip_atomic_store(&flags[wg * 16], t + 1,
                               __ATOMIC_RELEASE, __HIP_MEMORY_SCOPE_AGENT);

        // (G) convert + write x_{t+1} into the other x buffer
        #pragma unroll
        for (int i = 0; i < 4; ++i) {
            int cid = i * 512 + tid;
            int b = cid >> 5, k8 = cid & 31;
            f32x4 v0 = xv[2 * i], v1 = xv[2 * i + 1];
            u32x4 pk;
            pk.x = pk2h(v0[0], v0[1]); pk.y = pk2h(v0[2], v0[3]);
            pk.z = pk2h(v1[0], v1[1]); pk.w = pk2h(v1[2], v1[3]);
            *(u32x4*)&BSc[(((t + 1) & 1) * 2048 + k8 * 64 + (b ^ (k8 & 7))) * 16] = pk;
        }

        // (H) wait for all WGs to publish step t+1's h
        if (tid < NWG) {
            while (__hip_atomic_load(&flags[tid * 16],
                                     __ATOMIC_ACQUIRE, __HIP_MEMORY_SCOPE_AGENT) < t + 1) {}
        }
        __syncthreads();
    }
}

// ---------- fallback (R2-style, direct f32) if ws too small ----------
typedef __attribute__((ext_vector_type(4))) float f4_;
__global__ __launch_bounds__(HH, 1) void lstm_fallback(
    const float* __restrict__ x,   const float* __restrict__ h0,  const float* __restrict__ c0,
    const float* __restrict__ Wfi, const float* __restrict__ bfi,
    const float* __restrict__ Wfh, const float* __restrict__ bfh,
    const float* __restrict__ Wii, const float* __restrict__ bii,
    const float* __restrict__ Wih, const float* __restrict__ bih,
    const float* __restrict__ Wci, const float* __restrict__ bci,
    const float* __restrict__ Wch, const float* __restrict__ bch,
    const float* __restrict__ Woi, const float* __restrict__ boi,
    const float* __restrict__ Woh, const float* __restrict__ boh,
    float* __restrict__ out)
{
    const int b = blockIdx.x, j = threadIdx.x;
    __shared__ float xs[II];
    __shared__ float hs[HH];
    hs[j] = h0[b * HH + j];
    float c = c0[b * HH + j];
    const float bf_ = bfi[j] + bfh[j], bi_ = bii[j] + bih[j];
    const float bc_ = bci[j] + bch[j], bo_ = boi[j] + boh[j];
    const float *wfx = Wfi + j * II, *wix = Wii + j * II, *wcx = Wci + j * II, *wox = Woi + j * II;
    const float *wfh = Wfh + j * HH, *wih = Wih + j * HH, *wch = Wch + j * HH, *woh = Woh + j * HH;
    float hnew = 0.0f;
    for (int t = 0; t < SS; ++t) {
        if (t) hs[j] = hnew;
        if (j < II) xs[j] = x[(t * BB + b) * II + j];
        __syncthreads();
        float af = bf_, ai = bi_, ac = bc_, ao = bo_;
        #pragma unroll 4
        for (int k = 0; k < II; k += 4) {
            const f4_ wf = *(const f4_*)(wfx + k), wi = *(const f4_*)(wix + k);
            const f4_ wc = *(const f4_*)(wcx + k), wo = *(const f4_*)(wox + k);
            const f4_ xv = *(const f4_*)(xs + k);
            #pragma unroll
            for (int r = 0; r < 4; ++r) {
                af = fmaf(wf[r], xv[r], af); ai = fmaf(wi[r], xv[r], ai);
                ac = fmaf(wc[r], xv[r], ac); ao = fmaf(wo[r], xv[r], ao);
            }
        }
        #pragma unroll 4
        for (int k = 0; k < HH; k += 4) {
            const f4_ wf = *(const f4_*)(wfh + k), wi = *(const f4_*)(wih + k);
            const f4_ wc = *(const f4_*)(wch + k), wo = *(const f4_*)(woh + k);
            const f4_ hv = *(const f4_*)(hs + k);
            #pragma unroll
            for (int r = 0; r < 4; ++r) {
                af = fmaf(wf[r], hv[r], af); ai = fmaf(wi[r], hv[r], ai);
                ac = fmaf(wc[r], hv[r], ac); ao = fmaf(wo[r], hv[r], ao);
            }
        }
        const float fg = sigf(af), ig = sigf(ai), cg = tanhf_(ac), og = sigf(ao);
        c = c * fg + ig * cg;
        hnew = og * tanhf_(c);
        out[(t * BB + b) * HH + j] = hnew;
        __syncthreads();
    }
    out[SS * BB * HH + b * HH + j] = hnew;
    out[SS * BB * HH + BB * HH + b * HH + j] = c;
}

extern "C" void kernel_launch(void* const* d_in, const int* in_sizes, int n_in,
                              void* d_out, int out_size, void* d_ws, size_t ws_size,
                              hipStream_t stream) {
    const float* x   = (const float*)d_in[0];
    const float* h0  = (const float*)d_in[1];
    const float* c0  = (const float*)d_in[2];
    const float* Wfi = (const float*)d_in[3];
    const float* bfi = (const float*)d_in[4];
    const float* Wfh = (const float*)d_in[5];
    const float* bfh = (const float*)d_in[6];
    const float* Wii = (const float*)d_in[7];
    const float* bii = (const float*)d_in[8];
    const float* Wih = (const float*)d_in[9];
    const float* bih = (const float*)d_in[10];
    const float* Wci = (const float*)d_in[11];
    const float* bci = (const float*)d_in[12];
    const float* Wch = (const float*)d_in[13];
    const float* bch = (const float*)d_in[14];
    const float* Woi = (const float*)d_in[15];
    const float* boi = (const float*)d_in[16];
    const float* Woh = (const float*)d_in[17];
    const float* boh = (const float*)d_in[18];

    if (ws_size >= WS_NEED) {
        u32* A     = (u32*)d_ws;
        u16* hbb   = (u16*)((char*)d_ws + HB_OFF);
        int* flags = (int*)((char*)d_ws + FL_OFF);
        prep_A<<<dim3(A_DWORDS / 256), dim3(256), 0, stream>>>(
            Wfi, Wfh, Wii, Wih, Wci, Wch, Woi, Woh, A);
        prep_misc<<<dim3(128), dim3(256), 0, stream>>>(h0, hbb, flags);
        lstm_mfma<<<dim3(NWG), dim3(512), 0, stream>>>(
            x, c0, bfi, bfh, bii, bih, bci, bch, boi, boh,
            A, hbb, flags, (float*)d_out);
    } else {
        lstm_fallback<<<dim3(BB), dim3(HH), 0, stream>>>(
            x, h0, c0, Wfi, bfi, Wfh, bfh, Wii, bii, Wih, bih,
            Wci, bci, Wch, bch, Woi, boi, Woh, boh, (float*)d_out);
    }
}

// Round 5
// 2629.430 us; speedup vs baseline: 36.4204x; 3.0374x over previous
//
#include <hip/hip_runtime.h>

// LSTM S=512,B=64,I=256,H=512 (f32 buffers).
// R5: R4 (8ms) was sync-bound: RELEASE flag -> buffer_wbl2 (write back whole
// dirty L2, incl out[] HBM writes) + ACQUIRE -> buffer_inv, every step.
// Fix: fence-free protocol. h-exchange (hb) + flags use RELAXED agent-scope
// atomics only (sc0 sc1 = L1/L2 bypass, coherent at L3). Ordering:
// writer: hb sc1-stores -> __syncthreads (implicit s_waitcnt vmcnt(0)) ->
// flag sc1-store. reader: spin flag (relaxed) -> control-dep sc1 data loads
// (+ compiler barrier). No L2 writeback/invalidate anywhere.
// Also: GL gate-exchange de-atomic'd (2 plain-store buffers, summed in
// pointwise), GL overlaid on the idle x-double-buffer half (LDS 128KB).

#define SS 512
#define BB 64
#define II 256
#define HH 512
#define NWG 32
#define KT 24            // K-tiles of 16 per wave (K/2 = 384)

typedef unsigned int u32;
typedef unsigned short u16;
typedef unsigned long long u64;
typedef _Float16 __attribute__((ext_vector_type(8))) h16x8;
typedef __attribute__((ext_vector_type(2))) float f32x2;
typedef __attribute__((ext_vector_type(4))) float f32x4;
typedef __attribute__((ext_vector_type(16))) float f32x16;
typedef u32 __attribute__((ext_vector_type(4))) u32x4;

// ws layout (bytes): [A frags: 3,145,728][hb: 2*65,536][flags: 4096]
#define A_DWORDS (NWG * 2 * 2 * KT * 64 * 4)          // 786432
#define HB_OFF   ((size_t)A_DWORDS * 4)               // 3,145,728
#define FL_OFF   (HB_OFF + 2 * (size_t)BB * HH * 2)   // +131,072
#define WS_NEED  (FL_OFF + 4096)

__device__ __forceinline__ u32 pk2h(float a, float b) {
    union { _Float16 h[2]; u32 u; } v;
    v.h[0] = (_Float16)a; v.h[1] = (_Float16)b; return v.u;
}
__device__ __forceinline__ u16 f2h(float a) {
    union { _Float16 h; u16 u; } v; v.h = (_Float16)a; return v.u;
}
__device__ __forceinline__ float sigf(float v)  { return 1.0f / (1.0f + __expf(-v)); }
__device__ __forceinline__ float tanhf_(float v){ return 1.0f - 2.0f / (1.0f + __expf(2.0f * v)); }

// relaxed agent-scope (coherent-at-L3, no fences)
__device__ __forceinline__ void st_u32_coh(u32* p, u32 v) {
    __hip_atomic_store(p, v, __ATOMIC_RELAXED, __HIP_MEMORY_SCOPE_AGENT);
}
__device__ __forceinline__ void st_i32_coh(int* p, int v) {
    __hip_atomic_store(p, v, __ATOMIC_RELAXED, __HIP_MEMORY_SCOPE_AGENT);
}
__device__ __forceinline__ int ld_i32_coh(const int* p) {
    return __hip_atomic_load(p, __ATOMIC_RELAXED, __HIP_MEMORY_SCOPE_AGENT);
}
__device__ __forceinline__ u64 ld_u64_coh(const u64* p) {
    return __hip_atomic_load(p, __ATOMIC_RELAXED, __HIP_MEMORY_SCOPE_AGENT);
}

// ---------- prep: pack W into per-lane A-fragments (f16), K-major ----------
// A dword index = ((((wg*2+mt)*2+ks)*KT+kt)*64+l)*4+d
__global__ __launch_bounds__(256) void prep_A(
    const float* __restrict__ Wfi, const float* __restrict__ Wfh,
    const float* __restrict__ Wii, const float* __restrict__ Wih,
    const float* __restrict__ Wci, const float* __restrict__ Wch,
    const float* __restrict__ Woi, const float* __restrict__ Woh,
    u32* __restrict__ A)
{
    int tid = blockIdx.x * 256 + threadIdx.x;          // < 786432
    int wg = tid / 24576;  int r = tid - wg * 24576;
    int mt = r / 12288;    r -= mt * 12288;
    int ks = r / 6144;     r -= ks * 6144;
    int kt = r / 256;      r -= kt * 256;
    int l  = r >> 2;       int d = r & 3;

    int row = mt * 32 + (l & 31);
    int g   = row >> 4;
    int j   = wg * 16 + (row & 15);
    int k   = ks * 384 + kt * 16 + (l >> 5) * 8 + d * 2;

    const float* Wi = (g == 0) ? Wfi : (g == 1) ? Wii : (g == 2) ? Wci : Woi;
    const float* Wh = (g == 0) ? Wfh : (g == 1) ? Wih : (g == 2) ? Wch : Woh;
    float w0, w1;
    if (k < II) { w0 = Wi[j * II + k];        w1 = Wi[j * II + k + 1]; }
    else        { int kk = k - II; w0 = Wh[j * HH + kk]; w1 = Wh[j * HH + kk + 1]; }
    A[tid] = pk2h(w0, w1);
}

// ---------- prep: h0 -> f16 broadcast buffer, zero barrier flags ----------
__global__ __launch_bounds__(256) void prep_misc(
    const float* __restrict__ h0, u16* __restrict__ hb, int* __restrict__ flags)
{
    int tid = blockIdx.x * 256 + threadIdx.x;          // < 32768
    if (tid < BB * HH) {
        int b = tid >> 9, j = tid & 511;
        hb[(j >> 3) * 512 + b * 8 + (j & 7)] = f2h(h0[tid]);
    }
    if (tid < NWG) flags[tid * 32] = 0;
}

// ---------- main persistent cooperative kernel ----------
__global__ __launch_bounds__(512, 1) void lstm_mfma(
    const float* __restrict__ x,  const float* __restrict__ c0,
    const float* __restrict__ bfi, const float* __restrict__ bfh,
    const float* __restrict__ bii, const float* __restrict__ bih,
    const float* __restrict__ bci, const float* __restrict__ bch,
    const float* __restrict__ boi, const float* __restrict__ boh,
    const u32* __restrict__ A, u16* __restrict__ hb, int* __restrict__ flags,
    float* __restrict__ out)
{
    const int wg   = blockIdx.x;
    const int tid  = threadIdx.x;
    const int lane = tid & 63;
    const int w    = tid >> 6;
    const int mt   = w & 1;          // row-tile (32 gate-rows)
    const int nt2  = (w >> 1) & 1;   // batch-tile (32 batches)
    const int ks   = w >> 2;         // k-split half (K=384 each)
    const int khi  = lane >> 5;      // k-subhalf within fragment
    const int nb   = nt2 * 32 + (lane & 31);  // batch column this lane computes

    // BS chunks of 16B: [0,2048)=x buf0, [2048,4096)=x buf1, [4096,8192)=h.
    // The idle x buffer doubles as GL (gate-exchange, 2x64x64 f32 = 32KB).
    __shared__ __align__(16) u16 BS[8192 * 8];
    char* BSc = (char*)BS;

    // --- load A fragments (held in VGPRs for the whole kernel) ---
    h16x8 afr[KT];
    {
        const u32* ab = A + ((wg * 2 + mt) * 2 + ks) * (KT * 256) + lane * 4;
        #pragma unroll
        for (int kt = 0; kt < KT; ++kt)
            afr[kt] = *(const h16x8*)(ab + kt * 256);
    }

    // --- accumulator init: combined biases (only ks==0 carries bias) ---
    f32x16 acc_init;
    #pragma unroll
    for (int rg = 0; rg < 16; ++rg) {
        int row = mt * 32 + (rg & 3) + 8 * (rg >> 2) + 4 * khi;
        float bv = 0.0f;
        if (ks == 0) {
            int g = row >> 4, j = wg * 16 + (row & 15);
            const float* bi = (g == 0) ? bfi : (g == 1) ? bii : (g == 2) ? bci : boi;
            const float* bh = (g == 0) ? bfh : (g == 1) ? bih : (g == 2) ? bch : boh;
            bv = bi[j] + bh[j];
        }
        acc_init[rg] = bv;
    }

    // --- c state: thread owns (b = tid&63, j = wg*16 + 2*(tid>>6) + {0,1}) ---
    const int bown = tid & 63;
    const int w8   = tid >> 6;
    const int j0   = wg * 16 + 2 * w8;
    float cst[2];
    {
        const f32x2 cv = *(const f32x2*)(c0 + bown * HH + j0);
        cst[0] = cv.x; cst[1] = cv.y;
    }

    // --- stage x_0 into x buf 0 ---
    #pragma unroll
    for (int i = 0; i < 4; ++i) {
        int cid = i * 512 + tid;
        int b = cid >> 5, k8 = cid & 31;
        const f32x4* sp = (const f32x4*)(x + b * II + k8 * 8);
        f32x4 v0 = sp[0], v1 = sp[1];
        u32x4 pk;
        pk.x = pk2h(v0[0], v0[1]); pk.y = pk2h(v0[2], v0[3]);
        pk.z = pk2h(v1[0], v1[1]); pk.w = pk2h(v1[2], v1[3]);
        *(u32x4*)&BSc[(k8 * 64 + (b ^ (k8 & 7))) * 16] = pk;
    }

    for (int t = 0; t < SS; ++t) {
        const int cur = t & 1;
        float* GLp = (float*)(BSc + (size_t)(cur ^ 1) * 2048 * 16);  // idle x buf

        // (A) restage h from hb[cur] via coherent u64 loads (L3-fresh)
        {
            const u16* hsrc = hb + cur * (BB * HH);
            u64 hr[16];
            #pragma unroll
            for (int it = 0; it < 8; ++it) {
                int cd = it * 512 + tid;                 // 0..4095 chunk id
                int k8h = cd >> 6, bpos = cd & 63;
                int b = bpos ^ (k8h & 7);
                const u64* p = (const u64*)(hsrc + k8h * 512 + b * 8);
                hr[2 * it]     = ld_u64_coh(p);
                hr[2 * it + 1] = ld_u64_coh(p + 1);
            }
            #pragma unroll
            for (int it = 0; it < 8; ++it) {
                int cd = it * 512 + tid;
                union { u64 q[2]; u32x4 v; } u;
                u.q[0] = hr[2 * it]; u.q[1] = hr[2 * it + 1];
                *(u32x4*)&BSc[(4096 + cd) * 16] = u.v;
            }
        }

        // x prefetch t+1 (issue global loads; convert+write at (G))
        f32x4 xv[8];
        if (t + 1 < SS) {
            const float* xt = x + (size_t)(t + 1) * BB * II;
            #pragma unroll
            for (int i = 0; i < 4; ++i) {
                int cid = i * 512 + tid;
                int b = cid >> 5, k8 = cid & 31;
                const f32x4* sp = (const f32x4*)(xt + b * II + k8 * 8);
                xv[2 * i] = sp[0]; xv[2 * i + 1] = sp[1];
            }
        }

        __syncthreads();   // (B) h + x[cur] staged

        // (C) K-loop: 24 MFMAs (K=384 per k-split half)
        f32x16 acc = acc_init;
        #pragma unroll
        for (int kt = 0; kt < KT; ++kt) {
            int k8g = ks * 48 + kt * 2 + khi;
            int off;
            if (k8g < 32) { int q = k8g & 7;                     // x region
                off = (cur * 2048 + k8g * 64 + ((nb ^ q))) * 16;
            } else {        int k8h = k8g - 32; int q = k8h & 7; // h region
                off = (4096 + k8h * 64 + ((nb ^ q))) * 16;
            }
            h16x8 bf = *(const h16x8*)(BSc + off);
            acc = __builtin_amdgcn_mfma_f32_32x32x16_f16(afr[kt], bf, acc, 0, 0, 0);
        }

        // (C2) gate-exchange: plain disjoint stores, GL[ks][row 0..63][nb]
        #pragma unroll
        for (int rg = 0; rg < 16; ++rg) {
            int row = mt * 32 + (rg & 3) + 8 * (rg >> 2) + 4 * khi;
            GLp[ks * 4096 + row * 64 + nb] = acc[rg];
        }
        __syncthreads();   // (D)

        // (E) pointwise: thread owns (bown, j0) and (bown, j0+1)
        float hv2[2];
        #pragma unroll
        for (int i = 0; i < 2; ++i) {
            int m = 2 * w8 + i;
            float af = GLp[(0 * 16 + m) * 64 + bown] + GLp[4096 + (0 * 16 + m) * 64 + bown];
            float ai = GLp[(1 * 16 + m) * 64 + bown] + GLp[4096 + (1 * 16 + m) * 64 + bown];
            float ac = GLp[(2 * 16 + m) * 64 + bown] + GLp[4096 + (2 * 16 + m) * 64 + bown];
            float ao = GLp[(3 * 16 + m) * 64 + bown] + GLp[4096 + (3 * 16 + m) * 64 + bown];
            float fg = sigf(af), ig = sigf(ai), cg = tanhf_(ac), og = sigf(ao);
            float cn = cst[i] * fg + ig * cg;
            cst[i] = cn;
            hv2[i] = og * tanhf_(cn);
        }
        {
            f32x2 ho; ho.x = hv2[0]; ho.y = hv2[1];
            *(f32x2*)(out + ((size_t)t * BB + bown) * HH + j0) = ho;
        }
        // publish h (coherent u32 store into hb[(t+1)&1])
        st_u32_coh((u32*)(hb + ((t + 1) & 1) * (BB * HH) + (j0 >> 3) * 512 + bown * 8 + (j0 & 7)),
                   pk2h(hv2[0], hv2[1]));

        if (t == SS - 1) {
            f32x2 ho; ho.x = hv2[0]; ho.y = hv2[1];
            f32x2 co; co.x = cst[0]; co.y = cst[1];
            *(f32x2*)(out + (size_t)SS * BB * HH + bown * HH + j0) = ho;
            *(f32x2*)(out + (size_t)SS * BB * HH + BB * HH + bown * HH + j0) = co;
            break;
        }

        // (F) all hb stores drained (syncthreads emits vmcnt(0)), then flag
        __syncthreads();
        if (tid == 0) st_i32_coh(&flags[wg * 32], t + 1);

        // (G) convert + write x_{t+1} into the other x buffer (over GL)
        #pragma unroll
        for (int i = 0; i < 4; ++i) {
            int cid = i * 512 + tid;
            int b = cid >> 5, k8 = cid & 31;
            f32x4 v0 = xv[2 * i], v1 = xv[2 * i + 1];
            u32x4 pk;
            pk.x = pk2h(v0[0], v0[1]); pk.y = pk2h(v0[2], v0[3]);
            pk.z = pk2h(v1[0], v1[1]); pk.w = pk2h(v1[2], v1[3]);
            *(u32x4*)&BSc[((cur ^ 1) * 2048 + k8 * 64 + (b ^ (k8 & 7))) * 16] = pk;
        }

        // (H) wait for all WGs to publish step t+1's h (relaxed spin)
        if (tid < NWG) {
            while (ld_i32_coh(&flags[tid * 32]) < t + 1) {}
        }
        asm volatile("" ::: "memory");
        __syncthreads();
    }
}

// ---------- fallback (R2-style, direct f32) if ws too small ----------
typedef __attribute__((ext_vector_type(4))) float f4_;
__global__ __launch_bounds__(HH, 1) void lstm_fallback(
    const float* __restrict__ x,   const float* __restrict__ h0,  const float* __restrict__ c0,
    const float* __restrict__ Wfi, const float* __restrict__ bfi,
    const float* __restrict__ Wfh, const float* __restrict__ bfh,
    const float* __restrict__ Wii, const float* __restrict__ bii,
    const float* __restrict__ Wih, const float* __restrict__ bih,
    const float* __restrict__ Wci, const float* __restrict__ bci,
    const float* __restrict__ Wch, const float* __restrict__ bch,
    const float* __restrict__ Woi, const float* __restrict__ boi,
    const float* __restrict__ Woh, const float* __restrict__ boh,
    float* __restrict__ out)
{
    const int b = blockIdx.x, j = threadIdx.x;
    __shared__ float xs[II];
    __shared__ float hs[HH];
    hs[j] = h0[b * HH + j];
    float c = c0[b * HH + j];
    const float bf_ = bfi[j] + bfh[j], bi_ = bii[j] + bih[j];
    const float bc_ = bci[j] + bch[j], bo_ = boi[j] + boh[j];
    const float *wfx = Wfi + j * II, *wix = Wii + j * II, *wcx = Wci + j * II, *wox = Woi + j * II;
    const float *wfh = Wfh + j * HH, *wih = Wih + j * HH, *wch = Wch + j * HH, *woh = Woh + j * HH;
    float hnew = 0.0f;
    for (int t = 0; t < SS; ++t) {
        if (t) hs[j] = hnew;
        if (j < II) xs[j] = x[(t * BB + b) * II + j];
        __syncthreads();
        float af = bf_, ai = bi_, ac = bc_, ao = bo_;
        #pragma unroll 4
        for (int k = 0; k < II; k += 4) {
            const f4_ wf = *(const f4_*)(wfx + k), wi = *(const f4_*)(wix + k);
            const f4_ wc = *(const f4_*)(wcx + k), wo = *(const f4_*)(wox + k);
            const f4_ xv = *(const f4_*)(xs + k);
            #pragma unroll
            for (int r = 0; r < 4; ++r) {
                af = fmaf(wf[r], xv[r], af); ai = fmaf(wi[r], xv[r], ai);
                ac = fmaf(wc[r], xv[r], ac); ao = fmaf(wo[r], xv[r], ao);
            }
        }
        #pragma unroll 4
        for (int k = 0; k < HH; k += 4) {
            const f4_ wf = *(const f4_*)(wfh + k), wi = *(const f4_*)(wih + k);
            const f4_ wc = *(const f4_*)(wch + k), wo = *(const f4_*)(woh + k);
            const f4_ hv = *(const f4_*)(hs + k);
            #pragma unroll
            for (int r = 0; r < 4; ++r) {
                af = fmaf(wf[r], hv[r], af); ai = fmaf(wi[r], hv[r], ai);
                ac = fmaf(wc[r], hv[r], ac); ao = fmaf(wo[r], hv[r], ao);
            }
        }
        const float fg = sigf(af), ig = sigf(ai), cg = tanhf_(ac), og = sigf(ao);
        c = c * fg + ig * cg;
        hnew = og * tanhf_(c);
        out[(t * BB + b) * HH + j] = hnew;
        __syncthreads();
    }
    out[SS * BB * HH + b * HH + j] = hnew;
    out[SS * BB * HH + BB * HH + b * HH + j] = c;
}

extern "C" void kernel_launch(void* const* d_in, const int* in_sizes, int n_in,
                              void* d_out, int out_size, void* d_ws, size_t ws_size,
                              hipStream_t stream) {
    const float* x   = (const float*)d_in[0];
    const float* h0  = (const float*)d_in[1];
    const float* c0  = (const float*)d_in[2];
    const float* Wfi = (const float*)d_in[3];
    const float* bfi = (const float*)d_in[4];
    const float* Wfh = (const float*)d_in[5];
    const float* bfh = (const float*)d_in[6];
    const float* Wii = (const float*)d_in[7];
    const float* bii = (const float*)d_in[8];
    const float* Wih = (const float*)d_in[9];
    const float* bih = (const float*)d_in[10];
    const float* Wci = (const float*)d_in[11];
    const float* bci = (const float*)d_in[12];
    const float* Wch = (const float*)d_in[13];
    const float* bch = (const float*)d_in[14];
    const float* Woi = (const float*)d_in[15];
    const float* boi = (const float*)d_in[16];
    const float* Woh = (const float*)d_in[17];
    const float* boh = (const float*)d_in[18];

    if (ws_size >= WS_NEED) {
        u32* A     = (u32*)d_ws;
        u16* hbb   = (u16*)((char*)d_ws + HB_OFF);
        int* flags = (int*)((char*)d_ws + FL_OFF);
        prep_A<<<dim3(A_DWORDS / 256), dim3(256), 0, stream>>>(
            Wfi, Wfh, Wii, Wih, Wci, Wch, Woi, Woh, A);
        prep_misc<<<dim3(128), dim3(256), 0, stream>>>(h0, hbb, flags);
        lstm_mfma<<<dim3(NWG), dim3(512), 0, stream>>>(
            x, c0, bfi, bfh, bii, bih, bci, bch, boi, boh,
            A, hbb, flags, (float*)d_out);
    } else {
        lstm_fallback<<<dim3(BB), dim3(HH), 0, stream>>>(
            x, h0, c0, Wfi, bfi, Wfh, bfh, Wii, bii, Wih, bih,
            Wci, bci, Wch, bch, Woi, boi, Woh, boh, (float*)d_out);
    }
}